// Round 1
// baseline (2292.035 us; speedup 1.0000x reference)
//
#include <hip/hip_runtime.h>

#define S 1024
#define D 768
#define NH 12
#define HD 64
#define DFF 3072
#define NL 4

typedef unsigned short u16;
typedef __attribute__((ext_vector_type(8))) short bf8;
typedef __attribute__((ext_vector_type(4))) float f32x4;

__device__ __forceinline__ float b2f(u16 h){ return __uint_as_float(((unsigned)h)<<16); }
__device__ __forceinline__ u16 f2b(float f){
  unsigned u = __float_as_uint(f);
  return (u16)((u + 0x7fffu + ((u>>16)&1u)) >> 16);   // round-to-nearest-even
}
__device__ __forceinline__ void unpack8(uint4 v, float* f){
  f[0]=__uint_as_float(v.x<<16); f[1]=__uint_as_float(v.x&0xffff0000u);
  f[2]=__uint_as_float(v.y<<16); f[3]=__uint_as_float(v.y&0xffff0000u);
  f[4]=__uint_as_float(v.z<<16); f[5]=__uint_as_float(v.z&0xffff0000u);
  f[6]=__uint_as_float(v.w<<16); f[7]=__uint_as_float(v.w&0xffff0000u);
}

// ---------------- fp32 -> bf16 convert ----------------
__global__ __launch_bounds__(256) void cvt_kernel(const float* __restrict__ in, u16* __restrict__ out, int n){
  int i = (blockIdx.x*256 + threadIdx.x)*4;
  if (i >= n) return;
  float4 v = *(const float4*)(in + i);
  ushort4 o; o.x=f2b(v.x); o.y=f2b(v.y); o.z=f2b(v.z); o.w=f2b(v.w);
  *(ushort4*)(out+i) = o;
}

// pack Wq/Wk/Wv into one (L,2304,768) bf16 matrix
__global__ __launch_bounds__(256) void pack_qkv_kernel(const float* __restrict__ Wq, const float* __restrict__ Wk,
                                                       const float* __restrict__ Wv, u16* __restrict__ dst){
  const int per_layer = 2304*D;
  int i = (blockIdx.x*256 + threadIdx.x)*4;
  if (i >= NL*per_layer) return;
  int l = i / per_layer; int rem = i - l*per_layer;
  int r = rem / D, c = rem - r*D;
  const float* src;
  if (r < 768)       src = Wq + (size_t)l*D*D + (size_t)r*D + c;
  else if (r < 1536) src = Wk + (size_t)l*D*D + (size_t)(r-768)*D + c;
  else               src = Wv + (size_t)l*D*D + (size_t)(r-1536)*D + c;
  float4 v = *(const float4*)src;
  ushort4 o; o.x=f2b(v.x); o.y=f2b(v.y); o.z=f2b(v.z); o.w=f2b(v.w);
  *(ushort4*)(dst+i) = o;
}

// Rsum = rel_pos + rel_2d_pos + rel_2d_angle  (bf16 out)
__global__ __launch_bounds__(256) void rsum_kernel(const float* __restrict__ a, const float* __restrict__ b,
                                                   const float* __restrict__ c, u16* __restrict__ out){
  size_t i = ((size_t)blockIdx.x*256 + threadIdx.x)*4;
  float4 va = *(const float4*)(a+i);
  float4 vb = *(const float4*)(b+i);
  float4 vc = *(const float4*)(c+i);
  ushort4 o;
  o.x = f2b(va.x+vb.x+vc.x); o.y = f2b(va.y+vb.y+vc.y);
  o.z = f2b(va.z+vb.z+vc.z); o.w = f2b(va.w+vb.w+vc.w);
  *(ushort4*)(out+i) = o;
}

// ---------------- generic bf16 MFMA GEMM: C[m,n] = sum_k A[m,k]*B[n,k] ----------------
// MODE 0: QKV epilogue (q scaled bf16 head layout, k bf16 head layout, v fp32 head layout)
// MODE 1: +bias +res -> fp32 out (stride 768)
// MODE 2: gelu(+bias) -> bf16 out (stride 3072)
template<int MODE>
__global__ __launch_bounds__(256) void gemm_kernel(
    const u16* __restrict__ A, const u16* __restrict__ B, int K,
    const float* __restrict__ bias0, const float* __restrict__ bias1, const float* __restrict__ bias2,
    const float* __restrict__ res, float* __restrict__ outf, u16* __restrict__ outb,
    u16* __restrict__ qo, u16* __restrict__ ko, float* __restrict__ vo)
{
  int w = threadIdx.x >> 6, lane = threadIdx.x & 63;
  int quad = lane >> 4, l16 = lane & 15;
  int m0 = blockIdx.x*64 + (w&1)*32;
  int n0 = blockIdx.y*64 + (w>>1)*32;
  const u16* pa = A + (size_t)(m0 + l16)*K + quad*8;
  const u16* pb = B + (size_t)(n0 + l16)*K + quad*8;
  const size_t a16 = (size_t)16*K, b16 = (size_t)16*K;

  f32x4 accs[2][2];
  #pragma unroll
  for (int i=0;i<2;i++)
    #pragma unroll
    for (int j=0;j<2;j++){ accs[i][j][0]=0.f; accs[i][j][1]=0.f; accs[i][j][2]=0.f; accs[i][j][3]=0.f; }

  bf8 a0 = *(const bf8*)pa,        a1 = *(const bf8*)(pa + a16);
  bf8 b0 = *(const bf8*)pb,        b1 = *(const bf8*)(pb + b16);
  for (int k0 = 32; k0 < K; k0 += 32){
    bf8 na0 = *(const bf8*)(pa + k0), na1 = *(const bf8*)(pa + a16 + k0);
    bf8 nb0 = *(const bf8*)(pb + k0), nb1 = *(const bf8*)(pb + b16 + k0);
    accs[0][0] = __builtin_amdgcn_mfma_f32_16x16x32_bf16(a0,b0,accs[0][0],0,0,0);
    accs[0][1] = __builtin_amdgcn_mfma_f32_16x16x32_bf16(a0,b1,accs[0][1],0,0,0);
    accs[1][0] = __builtin_amdgcn_mfma_f32_16x16x32_bf16(a1,b0,accs[1][0],0,0,0);
    accs[1][1] = __builtin_amdgcn_mfma_f32_16x16x32_bf16(a1,b1,accs[1][1],0,0,0);
    a0=na0; a1=na1; b0=nb0; b1=nb1;
  }
  accs[0][0] = __builtin_amdgcn_mfma_f32_16x16x32_bf16(a0,b0,accs[0][0],0,0,0);
  accs[0][1] = __builtin_amdgcn_mfma_f32_16x16x32_bf16(a0,b1,accs[0][1],0,0,0);
  accs[1][0] = __builtin_amdgcn_mfma_f32_16x16x32_bf16(a1,b0,accs[1][0],0,0,0);
  accs[1][1] = __builtin_amdgcn_mfma_f32_16x16x32_bf16(a1,b1,accs[1][1],0,0,0);

  // C/D layout: col = lane&15 (n), row = quad*4 + reg (m)
  #pragma unroll
  for (int i=0;i<2;i++){
    #pragma unroll
    for (int j=0;j<2;j++){
      #pragma unroll
      for (int r=0;r<4;r++){
        int m = m0 + i*16 + quad*4 + r;
        int n = n0 + j*16 + l16;
        float val = accs[i][j][r];
        if (MODE == 0){
          if (n < 768){
            val += bias0[n];
            qo[((size_t)(n>>6)*S + m)*HD + (n&63)] = f2b(val*0.125f);
          } else if (n < 1536){
            int nn = n - 768; val += bias1[nn];
            ko[((size_t)(nn>>6)*S + m)*HD + (nn&63)] = f2b(val);
          } else {
            int nn = n - 1536; val += bias2[nn];
            vo[((size_t)(nn>>6)*S + m)*HD + (nn&63)] = val;
          }
        } else if (MODE == 1){
          val += bias0[n] + res[(size_t)m*768 + n];
          outf[(size_t)m*768 + n] = val;
        } else {
          val += bias0[n];
          float g = 0.5f*val*(1.0f + erff(val*0.70710678118f));
          outb[(size_t)m*DFF + n] = f2b(g);
        }
      }
    }
  }
}

// ---------------- LayerNorm: block per row ----------------
__global__ __launch_bounds__(256) void ln_kernel(const float* __restrict__ in, const float* __restrict__ g,
                                                 const float* __restrict__ bb, float* __restrict__ outf,
                                                 u16* __restrict__ outb){
  int row = blockIdx.x, t = threadIdx.x;
  int w = t>>6, lane = t&63;
  const float* x = in + (size_t)row*D;
  float v0 = x[t], v1 = x[t+256], v2 = x[t+512];
  float s = v0+v1+v2;
  #pragma unroll
  for (int m=32;m;m>>=1) s += __shfl_xor(s, m);
  __shared__ float red[8];
  if (lane==0) red[w] = s;
  __syncthreads();
  float mu = (red[0]+red[1]+red[2]+red[3]) * (1.0f/768.0f);
  float d0=v0-mu, d1=v1-mu, d2=v2-mu;
  float s2 = d0*d0+d1*d1+d2*d2;
  #pragma unroll
  for (int m=32;m;m>>=1) s2 += __shfl_xor(s2, m);
  if (lane==0) red[4+w] = s2;
  __syncthreads();
  float var = (red[4]+red[5]+red[6]+red[7]) * (1.0f/768.0f);
  float rs = rsqrtf(var + 1e-12f);
  float y0 = d0*rs*g[t]     + bb[t];
  float y1 = d1*rs*g[t+256] + bb[t+256];
  float y2 = d2*rs*g[t+512] + bb[t+512];
  size_t base = (size_t)row*D;
  outf[base+t]=y0; outf[base+t+256]=y1; outf[base+t+512]=y2;
  outb[base+t]=f2b(y0); outb[base+t+256]=f2b(y1); outb[base+t+512]=f2b(y2);
}

// ---------------- s1: scoresR[n,s,k] = q[n,s]·Rsum[s,k]  (all heads per R read) ----------------
__global__ __launch_bounds__(256) void s1_kernel(const u16* __restrict__ qb, const u16* __restrict__ R,
                                                 u16* __restrict__ sr){
  int s = blockIdx.x, t = threadIdx.x;
  __shared__ float qs[NH*HD];
  for (int i=t; i<NH*HD; i+=256)
    qs[i] = b2f(qb[(size_t)(i>>6)*S*HD + (size_t)s*HD + (i&63)]);
  __syncthreads();
  float acc[NH][4];
  #pragma unroll
  for (int n=0;n<NH;n++){ acc[n][0]=0.f; acc[n][1]=0.f; acc[n][2]=0.f; acc[n][3]=0.f; }
  const uint4* Rp = (const uint4*)(R + (size_t)s*S*HD);
  for (int c=0;c<8;c++){
    float rf[4][8];
    #pragma unroll
    for (int ki=0;ki<4;ki++){
      uint4 rv = Rp[(size_t)(t + ki*256)*8 + c];
      unpack8(rv, rf[ki]);
    }
    #pragma unroll
    for (int n=0;n<NH;n++){
      const float* qp = &qs[n*HD + c*8];
      float4 qa = *(const float4*)qp;
      float4 qc = *(const float4*)(qp+4);
      #pragma unroll
      for (int ki=0;ki<4;ki++){
        acc[n][ki] += qa.x*rf[ki][0]+qa.y*rf[ki][1]+qa.z*rf[ki][2]+qa.w*rf[ki][3]
                    + qc.x*rf[ki][4]+qc.y*rf[ki][5]+qc.z*rf[ki][6]+qc.w*rf[ki][7];
      }
    }
  }
  #pragma unroll
  for (int n=0;n<NH;n++)
    #pragma unroll
    for (int ki=0;ki<4;ki++)
      sr[(size_t)n*S*S + (size_t)s*S + t + ki*256] = f2b(acc[n][ki]);
}

// ---------------- s2: fused QK^T + rel + mask + softmax + PV, block = (s-chunk 16, head) ----------------
__global__ __launch_bounds__(256) void s2_kernel(const u16* __restrict__ qb, const u16* __restrict__ kb,
                                                 const float* __restrict__ V, const u16* __restrict__ sr,
                                                 const float* __restrict__ mask, u16* __restrict__ ctx){
  __shared__ float sc[16*1024];          // exactly 64 KB
  int s0 = blockIdx.x*16, n = blockIdx.y;
  int t = threadIdx.x, w = t>>6, lane = t&63, quad = lane>>4, l16 = lane&15;

  // preload rel scores + mask
  const u16* srp = sr + ((size_t)n<<20) + (size_t)s0*S;
  for (int idx = t; idx < 2048; idx += 256){
    int si = idx >> 7; int kc = (idx & 127)*8;
    uint4 rv = *(const uint4*)(srp + (size_t)si*S + kc);
    float f[8]; unpack8(rv, f);
    float4 m0 = *(const float4*)(mask + kc);
    float4 m1 = *(const float4*)(mask + kc + 4);
    float* dst = &sc[si*1024 + kc];
    *(float4*)dst     = make_float4(f[0]+m0.x, f[1]+m0.y, f[2]+m0.z, f[3]+m0.w);
    *(float4*)(dst+4) = make_float4(f[4]+m1.x, f[5]+m1.y, f[6]+m1.z, f[7]+m1.w);
  }
  __syncthreads();

  // QK^T via MFMA: A = q tile (16 rows), B tiles = K rows
  const u16* qrow = qb + ((size_t)n*S + s0 + l16)*HD + quad*8;
  bf8 a_lo = *(const bf8*)qrow;
  bf8 a_hi = *(const bf8*)(qrow + 32);
  for (int kt = w; kt < 64; kt += 4){
    const u16* kp = kb + ((size_t)n*S + kt*16 + l16)*HD + quad*8;
    bf8 b_lo = *(const bf8*)kp;
    bf8 b_hi = *(const bf8*)(kp + 32);
    f32x4 acc; acc[0]=0.f; acc[1]=0.f; acc[2]=0.f; acc[3]=0.f;
    acc = __builtin_amdgcn_mfma_f32_16x16x32_bf16(a_lo, b_lo, acc, 0,0,0);
    acc = __builtin_amdgcn_mfma_f32_16x16x32_bf16(a_hi, b_hi, acc, 0,0,0);
    #pragma unroll
    for (int r=0;r<4;r++)
      sc[(quad*4+r)*1024 + kt*16 + l16] += acc[r];
  }
  __syncthreads();

  // softmax: wave w owns rows 4w..4w+3 (PB-relax == standard stable softmax)
  #pragma unroll
  for (int i=0;i<4;i++){
    int si = w*4 + i;
    float* row = &sc[si*1024];
    float x[16];
    float mx = -1e30f;
    #pragma unroll
    for (int u=0;u<16;u++){ x[u] = row[lane + u*64]; mx = fmaxf(mx, x[u]); }
    #pragma unroll
    for (int m=32;m;m>>=1) mx = fmaxf(mx, __shfl_xor(mx, m));
    float sum = 0.f;
    #pragma unroll
    for (int u=0;u<16;u++){ x[u] = __expf(x[u]-mx); sum += x[u]; }
    #pragma unroll
    for (int m=32;m;m>>=1) sum += __shfl_xor(sum, m);
    float rinv = 1.0f / sum;
    #pragma unroll
    for (int u=0;u<16;u++) row[lane + u*64] = x[u]*rinv;
  }
  __syncthreads();

  // PV: lane = hd, wave w covers rows 4w..4w+3, loop all k
  int hd = lane;
  const float* vp = V + (size_t)n*S*HD + hd;
  float o0=0.f,o1=0.f,o2=0.f,o3=0.f;
  const float* r0 = &sc[(w*4+0)*1024];
  const float* r1 = &sc[(w*4+1)*1024];
  const float* r2 = &sc[(w*4+2)*1024];
  const float* r3 = &sc[(w*4+3)*1024];
  for (int k=0;k<1024;k+=4){
    float4 p0 = *(const float4*)(r0 + k);
    float4 p1 = *(const float4*)(r1 + k);
    float4 p2 = *(const float4*)(r2 + k);
    float4 p3 = *(const float4*)(r3 + k);
    float va = vp[(size_t)k*HD], vb2 = vp[(size_t)(k+1)*HD], vc2 = vp[(size_t)(k+2)*HD], vd = vp[(size_t)(k+3)*HD];
    o0 += p0.x*va + p0.y*vb2 + p0.z*vc2 + p0.w*vd;
    o1 += p1.x*va + p1.y*vb2 + p1.z*vc2 + p1.w*vd;
    o2 += p2.x*va + p2.y*vb2 + p2.z*vc2 + p2.w*vd;
    o3 += p3.x*va + p3.y*vb2 + p3.z*vc2 + p3.w*vd;
  }
  size_t cb = (size_t)(s0 + w*4)*D + n*HD + hd;
  ctx[cb        ] = f2b(o0);
  ctx[cb +   D  ] = f2b(o1);
  ctx[cb + 2*D  ] = f2b(o2);
  ctx[cb + 3*D  ] = f2b(o3);
}

extern "C" void kernel_launch(void* const* d_in, const int* in_sizes, int n_in,
                              void* d_out, int out_size, void* d_ws, size_t ws_size,
                              hipStream_t stream) {
  (void)in_sizes; (void)n_in; (void)out_size; (void)ws_size;
  const float* hidden=(const float*)d_in[0];
  const float* amask =(const float*)d_in[1];
  const float* rel   =(const float*)d_in[2];
  const float* rel2  =(const float*)d_in[3];
  const float* rela  =(const float*)d_in[4];
  const float* Wq=(const float*)d_in[5];  const float* bq=(const float*)d_in[6];
  const float* Wk=(const float*)d_in[7];  const float* bk=(const float*)d_in[8];
  const float* Wv=(const float*)d_in[9];  const float* bv=(const float*)d_in[10];
  const float* Wo=(const float*)d_in[11]; const float* bo=(const float*)d_in[12];
  const float* g1=(const float*)d_in[13]; const float* be1=(const float*)d_in[14];
  const float* Wi=(const float*)d_in[15]; const float* bi=(const float*)d_in[16];
  const float* Wo2=(const float*)d_in[17];const float* bo2=(const float*)d_in[18];
  const float* g2=(const float*)d_in[19]; const float* be2=(const float*)d_in[20];

  char* wsp = (char*)d_ws; size_t off = 0;
  auto take = [&](size_t bytes)->char* { char* p = wsp + off; off += (bytes + 255) & ~(size_t)255; return p; };
  u16*   RS   = (u16*)  take((size_t)S*S*HD*2);      // 128 MB bf16 Rsum
  u16*   WQKV = (u16*)  take((size_t)NL*2304*D*2);
  u16*   WOb  = (u16*)  take((size_t)NL*D*D*2);
  u16*   WIb  = (u16*)  take((size_t)NL*DFF*D*2);
  u16*   WO2b = (u16*)  take((size_t)NL*D*DFF*2);
  u16*   HBF  = (u16*)  take((size_t)S*D*2);
  u16*   QB   = (u16*)  take((size_t)NH*S*HD*2);
  u16*   KB   = (u16*)  take((size_t)NH*S*HD*2);
  float* VF   = (float*)take((size_t)NH*S*HD*4);
  u16*   SR   = (u16*)  take((size_t)NH*S*S*2);      // 24 MB bf16 rel-scores
  u16*   CTXB = (u16*)  take((size_t)S*D*2);
  float* TMP  = (float*)take((size_t)S*D*4);
  float* ATT  = (float*)take((size_t)S*D*4);
  u16*   ATTB = (u16*)  take((size_t)S*D*2);
  u16*   INTB = (u16*)  take((size_t)S*DFF*2);
  float* HBUF = (float*)take((size_t)S*D*4);

  // one-time conversions
  pack_qkv_kernel<<<dim3(6912),256,0,stream>>>(Wq, Wk, Wv, WQKV);
  cvt_kernel<<<dim3(2304),256,0,stream>>>(Wo,  WOb,  NL*D*D);
  cvt_kernel<<<dim3(9216),256,0,stream>>>(Wi,  WIb,  NL*DFF*D);
  cvt_kernel<<<dim3(9216),256,0,stream>>>(Wo2, WO2b, NL*D*DFF);
  cvt_kernel<<<dim3(768), 256,0,stream>>>(hidden, HBF, S*D);
  rsum_kernel<<<dim3(65536),256,0,stream>>>(rel, rel2, rela, RS);

  const float* hres = hidden;
  for (int l=0;l<NL;l++){
    gemm_kernel<0><<<dim3(16,36),256,0,stream>>>(HBF, WQKV + (size_t)l*2304*D, D,
        bq + l*D, bk + l*D, bv + l*D, nullptr, nullptr, nullptr, QB, KB, VF);
    s1_kernel<<<dim3(1024),256,0,stream>>>(QB, RS, SR);
    s2_kernel<<<dim3(64,NH),256,0,stream>>>(QB, KB, VF, SR, amask, CTXB);
    gemm_kernel<1><<<dim3(16,12),256,0,stream>>>(CTXB, WOb + (size_t)l*D*D, D,
        bo + l*D, nullptr, nullptr, hres, TMP, nullptr, nullptr, nullptr, nullptr);
    ln_kernel<<<dim3(1024),256,0,stream>>>(TMP, g1 + l*D, be1 + l*D, ATT, ATTB);
    gemm_kernel<2><<<dim3(16,48),256,0,stream>>>(ATTB, WIb + (size_t)l*DFF*D, D,
        bi + l*DFF, nullptr, nullptr, nullptr, nullptr, INTB, nullptr, nullptr, nullptr);
    gemm_kernel<1><<<dim3(16,12),256,0,stream>>>(INTB, WO2b + (size_t)l*D*DFF, DFF,
        bo2 + l*D, nullptr, nullptr, ATT, TMP, nullptr, nullptr, nullptr, nullptr);
    float* hout = (l==NL-1) ? (float*)d_out : HBUF;
    ln_kernel<<<dim3(1024),256,0,stream>>>(TMP, g2 + l*D, be2 + l*D, hout, HBF);
    hres = HBUF;
  }
}